// Round 4
// baseline (532.271 us; speedup 1.0000x reference)
//
#include <hip/hip_runtime.h>
#include <cstdint>

// ---------------- problem constants ----------------
static constexpr int B_  = 8192;
static constexpr int NW_ = 192;                 // NS + NV

typedef __attribute__((ext_vector_type(8))) short s8v;
typedef __attribute__((ext_vector_type(4))) float f4v;
typedef __attribute__((ext_vector_type(2))) float f2v;
typedef __attribute__((ext_vector_type(4))) int i4v;
typedef __attribute__((ext_vector_type(4))) unsigned u4v;

#define DI __device__ __forceinline__

DI short f2bf_rne(float f) {
  unsigned u = __builtin_bit_cast(unsigned, f);
  u += 0x7FFFu + ((u >> 16) & 1u);               // round-to-nearest-even
  return (short)(u >> 16);
}
DI float bf2f(unsigned short h) {
  unsigned u = ((unsigned)h) << 16;
  return __builtin_bit_cast(float, u);
}
DI float ibitsf(int u) { return __builtin_bit_cast(float, u); }
DI float plo(int p) { return ibitsf(p << 16); }
DI float phi(int p) { return ibitsf((int)(p & 0xFFFF0000)); }
// pack bf16(lo), bf16(hi) with round-half-up: 2 adds + 1 v_perm
DI unsigned rpack(float lo, float hi) {
  unsigned ua = __builtin_bit_cast(unsigned, lo) + 0x8000u;
  unsigned ub = __builtin_bit_cast(unsigned, hi) + 0x8000u;
  return __builtin_amdgcn_perm(ub, ua, 0x07060302u);
}

// ---------------- prep: scalar-path weights, fragment-packed bf16 ----------------
// Wf[kt][nt(12)][lane(64)][j(8)] = W[k = kt*32 + (lane>>4)*8 + j][n = nt*16 + (lane&15)]
__global__ void prep_wsc(const float* __restrict__ w000, const float* __restrict__ w110,
                         short* __restrict__ wf) {
  int g = blockIdx.x * blockDim.x + threadIdx.x;  // 20480*192/8 threads exactly
  int l = g & 63;
  int nt = (g >> 6) % 12;
  int kt = g / (64 * 12);
  int n = nt * 16 + (l & 15);
  int kbase = kt * 32 + ((l >> 4) << 3);
  const float s000 = 1.0f / (128.0f * 1.41421356237f);   // (1/N0) * inv_sqrt2
  const float s110 = 1.0f / (64.0f * 2.44948974968f);    // (1/(N1*sqrt6 total))
  s8v o;
#pragma unroll
  for (int j = 0; j < 8; ++j) {
    int k = kbase + j;
    float v = (k < 16384) ? w000[(size_t)k * NW_ + n] * s000
                          : w110[(size_t)(k - 16384) * NW_ + n] * s110;
    o[j] = f2bf_rne(v);
  }
  *(s8v*)(wf + (size_t)g * 8) = o;
}

// ---------------- prep: vector-path weights, fragment-packed bf16 ----------------
__global__ void prep_wvec(const float* __restrict__ w011, const float* __restrict__ w111,
                          short* __restrict__ wf) {
  int g = blockIdx.x * blockDim.x + threadIdx.x;  // 12288*64/8 threads exactly
  int l = g & 63;
  int nt = (g >> 6) & 3;
  int kt = g >> 8;
  int n = nt * 16 + (l & 15);
  int kbase = kt * 32 + ((l >> 4) << 3);
  const float sv = 1.0f / 128.0f;  // both v011 and v111 total scales reduce to 1/128
  s8v o;
#pragma unroll
  for (int j = 0; j < 8; ++j) {
    int k = kbase + j;
    float v = (k < 8192) ? w011[(size_t)k * 64 + n] * sv
                         : w111[(size_t)(k - 8192) * 64 + n] * sv;
    o[j] = f2bf_rne(v);
  }
  *(s8v*)(wf + (size_t)g * 8) = o;
}

// ---------------- shared LDS staging: 64 rows of x ----------------
#define X0_STRIDE 132
#define X1_STRIDE 200

DI void stage_x(const float* __restrict__ x, int b0, float* X0, unsigned short* X1) {
  const int t = threadIdx.x;            // 512 threads
  const int row = t >> 3, l8 = t & 7;
  const float* src = x + (size_t)(b0 + row) * 320;
#pragma unroll
  for (int j = 0; j < 4; ++j) {
    int c = l8 * 16 + j * 4;
    *(f4v*)(&X0[row * X0_STRIDE + c]) = *(const f4v*)(src + c);
  }
  float buf[24];
#pragma unroll
  for (int j = 0; j < 12; ++j) {
    f2v v = *(const f2v*)(src + 128 + l8 * 24 + j * 2);
    buf[2 * j] = v.x; buf[2 * j + 1] = v.y;
  }
#pragma unroll
  for (int i = 0; i < 3; ++i) {
    u4v o;
#pragma unroll
    for (int e = 0; e < 4; ++e)
      o[e] = rpack(buf[(2 * e) * 3 + i], buf[(2 * e + 1) * 3 + i]);
    *(u4v*)(&X1[row * X1_STRIDE + i * 64 + l8 * 8]) = o;
  }
}

// ---------------- A-fragment generators ----------------
DI u4v agen_x0(const float* __restrict__ x0r, float xu, int vb) {
  f4v v0 = *(const f4v*)(x0r + vb);
  f4v v1 = *(const f4v*)(x0r + vb + 4);
  u4v pa;
  pa[0] = rpack(xu * v0.x, xu * v0.y);
  pa[1] = rpack(xu * v0.z, xu * v0.w);
  pa[2] = rpack(xu * v1.x, xu * v1.y);
  pa[3] = rpack(xu * v1.z, xu * v1.w);
  return pa;
}
DI u4v agen_dots(const unsigned short* __restrict__ x1r, int u, int vb) {
  float sm[8] = {0.f, 0.f, 0.f, 0.f, 0.f, 0.f, 0.f, 0.f};
#pragma unroll
  for (int i = 0; i < 3; ++i) {
    const float xu = bf2f(x1r[i * 64 + u]);
    i4v p = *(const i4v*)(x1r + i * 64 + vb);
#pragma unroll
    for (int m = 0; m < 4; ++m) {
      sm[2 * m]     += xu * plo(p[m]);
      sm[2 * m + 1] += xu * phi(p[m]);
    }
  }
  u4v pa;
  pa[0] = rpack(sm[0], sm[1]);
  pa[1] = rpack(sm[2], sm[3]);
  pa[2] = rpack(sm[4], sm[5]);
  pa[3] = rpack(sm[6], sm[7]);
  return pa;
}

// B-frag loaders (register ping-pong buffers)
DI void loadB6(s8v* dst, const short* __restrict__ wp, int t) {
#pragma unroll
  for (int nf = 0; nf < 6; ++nf)
    dst[nf] = *(const s8v*)(wp + (size_t)t * 6144 + nf * 512);
}
DI void loadB4(s8v* dst, const short* __restrict__ wp, int t) {
#pragma unroll
  for (int nf = 0; nf < 4; ++nf)
    dst[nf] = *(const s8v*)(wp + (size_t)t * 2048 + nf * 512);
}

// ---------------- scalar-path GEMM: C[8192,192] += A(gen) * Wsc ----------------
// block 64 rows x 192 cols; 8 waves = mg(2) x nh(2) x kh(2); wave = 2 m-frags x 6 n-frags
// balanced split-K: each (kb,kh) chunk = 64 x0-steps + 16 dots-steps (specialized loops)
__global__ __launch_bounds__(512, 4)
void gemm_sc(const float* __restrict__ x, const short* __restrict__ wf,
             float* __restrict__ acc_out) {
  __shared__ float X0[64 * X0_STRIDE];
  __shared__ unsigned short X1[64 * X1_STRIDE];
  const int kb = blockIdx.x & 3;
  const int b0 = (blockIdx.x >> 2) * 64;

  stage_x(x, b0, X0, X1);
  __syncthreads();

  const int t0 = threadIdx.x;
  const int w = t0 >> 6, lane = t0 & 63;
  const int mg = w & 1, nh = (w >> 1) & 1, kh = w >> 2;
  const int c = kb * 2 + kh;            // chunk 0..7
  const int q = lane >> 4, r = lane & 15, q8 = (lane >> 4) * 8;
  const int rowA = mg * 32 + r;
  const float* x0A = &X0[rowA * X0_STRIDE];
  const float* x0B = &X0[(rowA + 16) * X0_STRIDE];
  const unsigned short* x1A = &X1[rowA * X1_STRIDE];
  const unsigned short* x1B = &X1[(rowA + 16) * X1_STRIDE];

  f4v acc[2][6];
#pragma unroll
  for (int f = 0; f < 2; ++f)
#pragma unroll
    for (int nf = 0; nf < 6; ++nf) acc[f][nf] = f4v{0.f, 0.f, 0.f, 0.f};

  s8v bA[6], bB[6];

  // ---- region 1: x0 outer product, 64 steps (absolute s in [c*64, c*64+64)) ----
  {
    const int sAbs = c * 64;
    const int u0 = sAbs >> 2;            // u advances every 4 steps
    const short* wp = wf + (((size_t)sAbs * 12 + nh * 6) * 64 + lane) * 8;
    loadB6(bA, wp, 0);
    for (int t = 0; t < 64; t += 2) {
      loadB6(bB, wp, t + 1);
      {
        const int u = u0 + (t >> 2), vb = (t & 3) * 32 + q8;
        u4v pa0 = agen_x0(x0A, x0A[u], vb);
        u4v pa1 = agen_x0(x0B, x0B[u], vb);
        s8v a0 = __builtin_bit_cast(s8v, pa0), a1 = __builtin_bit_cast(s8v, pa1);
#pragma unroll
        for (int nf = 0; nf < 6; ++nf) {
          acc[0][nf] = __builtin_amdgcn_mfma_f32_16x16x32_bf16(a0, bA[nf], acc[0][nf], 0, 0, 0);
          acc[1][nf] = __builtin_amdgcn_mfma_f32_16x16x32_bf16(a1, bA[nf], acc[1][nf], 0, 0, 0);
        }
      }
      if (t + 2 < 64) loadB6(bA, wp, t + 2);
      {
        const int u = u0 + ((t + 1) >> 2), vb = ((t + 1) & 3) * 32 + q8;
        u4v pa0 = agen_x0(x0A, x0A[u], vb);
        u4v pa1 = agen_x0(x0B, x0B[u], vb);
        s8v a0 = __builtin_bit_cast(s8v, pa0), a1 = __builtin_bit_cast(s8v, pa1);
#pragma unroll
        for (int nf = 0; nf < 6; ++nf) {
          acc[0][nf] = __builtin_amdgcn_mfma_f32_16x16x32_bf16(a0, bB[nf], acc[0][nf], 0, 0, 0);
          acc[1][nf] = __builtin_amdgcn_mfma_f32_16x16x32_bf16(a1, bB[nf], acc[1][nf], 0, 0, 0);
        }
      }
    }
  }

  // ---- region 2: x1-dots, 16 steps (absolute s in [512 + c*16, +16)) ----
  {
    const int sAbs = 512 + c * 16;
    const int u0 = (sAbs - 512) >> 1;    // u advances every 2 steps
    const short* wp = wf + (((size_t)sAbs * 12 + nh * 6) * 64 + lane) * 8;
    loadB6(bA, wp, 0);
    for (int t = 0; t < 16; t += 2) {
      loadB6(bB, wp, t + 1);
      {
        const int u = u0 + (t >> 1), vb = (t & 1) * 32 + q8;
        u4v pa0 = agen_dots(x1A, u, vb);
        u4v pa1 = agen_dots(x1B, u, vb);
        s8v a0 = __builtin_bit_cast(s8v, pa0), a1 = __builtin_bit_cast(s8v, pa1);
#pragma unroll
        for (int nf = 0; nf < 6; ++nf) {
          acc[0][nf] = __builtin_amdgcn_mfma_f32_16x16x32_bf16(a0, bA[nf], acc[0][nf], 0, 0, 0);
          acc[1][nf] = __builtin_amdgcn_mfma_f32_16x16x32_bf16(a1, bA[nf], acc[1][nf], 0, 0, 0);
        }
      }
      if (t + 2 < 16) loadB6(bA, wp, t + 2);
      {
        const int u = u0 + ((t + 1) >> 1), vb = ((t + 1) & 1) * 32 + q8;
        u4v pa0 = agen_dots(x1A, u, vb);
        u4v pa1 = agen_dots(x1B, u, vb);
        s8v a0 = __builtin_bit_cast(s8v, pa0), a1 = __builtin_bit_cast(s8v, pa1);
#pragma unroll
        for (int nf = 0; nf < 6; ++nf) {
          acc[0][nf] = __builtin_amdgcn_mfma_f32_16x16x32_bf16(a0, bB[nf], acc[0][nf], 0, 0, 0);
          acc[1][nf] = __builtin_amdgcn_mfma_f32_16x16x32_bf16(a1, bB[nf], acc[1][nf], 0, 0, 0);
        }
      }
    }
  }

#pragma unroll
  for (int f = 0; f < 2; ++f)
#pragma unroll
    for (int nf = 0; nf < 6; ++nf) {
      int n = (nh * 6 + nf) * 16 + r;
#pragma unroll
      for (int reg = 0; reg < 4; ++reg) {
        int rowo = b0 + mg * 32 + f * 16 + q * 4 + reg;
        atomicAdd(&acc_out[(size_t)rowo * NW_ + n], acc[f][nf][reg]);
      }
    }
}

// ---------------- vector-path GEMM: C[3*8192, 64] += A(gen) * Wvec ----------------
// block 64 rows x (3 planes x 64 cols); 8 waves = mg(4) x kh(2); 12 MFMA/step
// balanced split-K: each chunk c = 32 x0x1-steps + 16 cross-steps
__global__ __launch_bounds__(512, 4)
void gemm_vec(const float* __restrict__ x, const short* __restrict__ wf,
              float* __restrict__ acc_out) {
  __shared__ float X0[64 * X0_STRIDE];
  __shared__ unsigned short X1[64 * X1_STRIDE];
  const int kb = blockIdx.x & 3;
  const int b0 = (blockIdx.x >> 2) * 64;

  stage_x(x, b0, X0, X1);
  __syncthreads();

  const int t0 = threadIdx.x;
  const int w = t0 >> 6, lane = t0 & 63;
  const int mg = w & 3, kh = w >> 2;
  const int c = kb * 2 + kh;            // chunk 0..7
  const int q = lane >> 4, r = lane & 15, q8 = (lane >> 4) * 8;
  const int row = mg * 16 + r;
  const float* x0r = &X0[row * X0_STRIDE];
  const unsigned short* x1r = &X1[row * X1_STRIDE];

  f4v acc[3][4];
#pragma unroll
  for (int ip = 0; ip < 3; ++ip)
#pragma unroll
    for (int nf = 0; nf < 4; ++nf) acc[ip][nf] = f4v{0.f, 0.f, 0.f, 0.f};

  s8v bA[4], bB[4];

  // ---- region 1: x0 * x1[ip], 32 steps (absolute s in [c*32, +32)) ----
  {
    const int sAbs = c * 32;
    const int u0 = sAbs >> 1;            // u advances every 2 steps
    const short* wp = wf + ((size_t)sAbs * 256 + lane) * 8;
    loadB4(bA, wp, 0);
    for (int t = 0; t < 32; t += 2) {
      loadB4(bB, wp, t + 1);
#pragma unroll
      for (int half = 0; half < 2; ++half) {
        if (half == 0) { /* uses bA */ } else { if (t + 2 < 32) loadB4(bA, wp, t + 2); }
        const int tt = t + half;
        const int u = u0 + (tt >> 1), vb = (tt & 1) * 32 + q8;
        const float xu = x0r[u];
        const s8v* bfr = (half == 0) ? bA : bB;
#pragma unroll
        for (int i = 0; i < 3; ++i) {
          i4v p = *(const i4v*)(x1r + i * 64 + vb);
          u4v pa;
#pragma unroll
          for (int m = 0; m < 4; ++m)
            pa[m] = rpack(xu * plo(p[m]), xu * phi(p[m]));
          s8v afr = __builtin_bit_cast(s8v, pa);
#pragma unroll
          for (int nf = 0; nf < 4; ++nf)
            acc[i][nf] = __builtin_amdgcn_mfma_f32_16x16x32_bf16(afr, bfr[nf], acc[i][nf], 0, 0, 0);
        }
      }
    }
  }

  // ---- region 2: cross products, 16 steps (absolute s in [256 + c*16, +16)) ----
  {
    const int sAbs = 256 + c * 16;
    const int u0 = (sAbs - 256) >> 1;
    const short* wp = wf + ((size_t)sAbs * 256 + lane) * 8;
    loadB4(bA, wp, 0);
    for (int t = 0; t < 16; t += 2) {
      loadB4(bB, wp, t + 1);
#pragma unroll
      for (int half = 0; half < 2; ++half) {
        if (half == 1) { if (t + 2 < 16) loadB4(bA, wp, t + 2); }
        const int tt = t + half;
        const int u = u0 + (tt >> 1), vb = (tt & 1) * 32 + q8;
        const s8v* bfr = (half == 0) ? bA : bB;
        float us[3];
        i4v p[3];
#pragma unroll
        for (int i = 0; i < 3; ++i) {
          us[i] = bf2f(x1r[i * 64 + u]);
          p[i] = *(const i4v*)(x1r + i * 64 + vb);
        }
#pragma unroll
        for (int ip = 0; ip < 3; ++ip) {
          const int i1 = (ip + 1) % 3, i2 = (ip + 2) % 3;
          u4v pa;
#pragma unroll
          for (int m = 0; m < 4; ++m) {
            float lo = us[i1] * plo(p[i2][m]) - us[i2] * plo(p[i1][m]);
            float hi = us[i1] * phi(p[i2][m]) - us[i2] * phi(p[i1][m]);
            pa[m] = rpack(lo, hi);
          }
          s8v afr = __builtin_bit_cast(s8v, pa);
#pragma unroll
          for (int nf = 0; nf < 4; ++nf)
            acc[ip][nf] = __builtin_amdgcn_mfma_f32_16x16x32_bf16(afr, bfr[nf], acc[ip][nf], 0, 0, 0);
        }
      }
    }
  }

#pragma unroll
  for (int ip = 0; ip < 3; ++ip)
#pragma unroll
    for (int nf = 0; nf < 4; ++nf) {
      int n = nf * 16 + r;
#pragma unroll
      for (int reg = 0; reg < 4; ++reg) {
        int rowo = ip * B_ + b0 + mg * 16 + q * 4 + reg;
        atomicAdd(&acc_out[(size_t)rowo * 64 + n], acc[ip][nf][reg]);
      }
    }
}

// ---------------- epilogue: silu / sigmoid-gating, interleaved output ----------------
__global__ void epilogue(const float* __restrict__ sc, const float* __restrict__ ve,
                         float* __restrict__ out) {
  int t = blockIdx.x * blockDim.x + threadIdx.x;  // B*192 threads exactly
  int b = t / NW_, c = t % NW_;
  float v = sc[t];
  float sg = 1.0f / (1.0f + __expf(-v));
  if (c < 128) {
    out[(size_t)b * 320 + c] = v * sg;            // silu
  } else {
    int w = c - 128;
#pragma unroll
    for (int i = 0; i < 3; ++i) {
      float vv = ve[((size_t)i * B_ + b) * 64 + w];
      out[(size_t)b * 320 + 128 + w * 3 + i] = vv * sg;
    }
  }
}

// ---------------- launch ----------------
extern "C" void kernel_launch(void* const* d_in, const int* in_sizes, int n_in,
                              void* d_out, int out_size, void* d_ws, size_t ws_size,
                              hipStream_t stream) {
  const float* x    = (const float*)d_in[0];
  const float* w000 = (const float*)d_in[1];
  const float* w110 = (const float*)d_in[2];
  const float* w011 = (const float*)d_in[3];
  const float* w111 = (const float*)d_in[4];
  float* out = (float*)d_out;

  char* ws = (char*)d_ws;
  float* acc_sc = (float*)ws;                     // 8192*192*4  = 6,291,456 B
  float* acc_ve = (float*)(ws + 6291456);         // 3*8192*64*4 = 6,291,456 B
  short* wsc    = (short*)(ws + 12582912);        // 20480*192*2 = 7,864,320 B
  short* wve    = (short*)(ws + 20447232);        // 12288*64*2  = 1,572,864 B

  (void)hipMemsetAsync(acc_sc, 0, 2 * 6291456, stream);  // zero both accumulators
  prep_wsc <<<1920, 256, 0, stream>>>(w000, w110, wsc);
  prep_wvec<<<384,  256, 0, stream>>>(w011, w111, wve);
  gemm_sc  <<<512, 512, 0, stream>>>(x, wsc, acc_sc);
  gemm_vec <<<512, 512, 0, stream>>>(x, wve, acc_ve);
  epilogue <<<6144, 256, 0, stream>>>(acc_sc, acc_ve, out);
}

// Round 5
// 412.369 us; speedup vs baseline: 1.2908x; 1.2908x over previous
//
#include <hip/hip_runtime.h>
#include <cstdint>

// ---------------- problem constants ----------------
static constexpr int B_  = 8192;
static constexpr int NW_ = 192;                 // NS + NV

typedef __attribute__((ext_vector_type(8))) short s8v;
typedef __attribute__((ext_vector_type(4))) float f4v;
typedef __attribute__((ext_vector_type(2))) float f2v;
typedef __attribute__((ext_vector_type(4))) int i4v;
typedef __attribute__((ext_vector_type(4))) unsigned u4v;

#define DI __device__ __forceinline__

DI short f2bf_rne(float f) {
  unsigned u = __builtin_bit_cast(unsigned, f);
  u += 0x7FFFu + ((u >> 16) & 1u);               // round-to-nearest-even
  return (short)(u >> 16);
}
DI float bf2f(unsigned short h) {
  unsigned u = ((unsigned)h) << 16;
  return __builtin_bit_cast(float, u);
}
DI float ibitsf(int u) { return __builtin_bit_cast(float, u); }
DI float plo(int p) { return ibitsf(p << 16); }
DI float phi(int p) { return ibitsf((int)(p & 0xFFFF0000)); }
// pack bf16(lo), bf16(hi) with round-half-up: 2 adds + 1 v_perm
DI unsigned rpack(float lo, float hi) {
  unsigned ua = __builtin_bit_cast(unsigned, lo) + 0x8000u;
  unsigned ub = __builtin_bit_cast(unsigned, hi) + 0x8000u;
  return __builtin_amdgcn_perm(ub, ua, 0x07060302u);
}

// ---------------- prep: scalar-path weights, fragment-packed bf16 ----------------
// Wf[kt][nt(12)][lane(64)][j(8)] = W[k = kt*32 + (lane>>4)*8 + j][n = nt*16 + (lane&15)]
__global__ void prep_wsc(const float* __restrict__ w000, const float* __restrict__ w110,
                         short* __restrict__ wf) {
  int g = blockIdx.x * blockDim.x + threadIdx.x;  // 20480*192/8 threads exactly
  int l = g & 63;
  int nt = (g >> 6) % 12;
  int kt = g / (64 * 12);
  int n = nt * 16 + (l & 15);
  int kbase = kt * 32 + ((l >> 4) << 3);
  const float s000 = 1.0f / (128.0f * 1.41421356237f);
  const float s110 = 1.0f / (64.0f * 2.44948974968f);
  s8v o;
#pragma unroll
  for (int j = 0; j < 8; ++j) {
    int k = kbase + j;
    float v = (k < 16384) ? w000[(size_t)k * NW_ + n] * s000
                          : w110[(size_t)(k - 16384) * NW_ + n] * s110;
    o[j] = f2bf_rne(v);
  }
  *(s8v*)(wf + (size_t)g * 8) = o;
}

// ---------------- prep: vector-path weights, fragment-packed bf16 ----------------
__global__ void prep_wvec(const float* __restrict__ w011, const float* __restrict__ w111,
                          short* __restrict__ wf) {
  int g = blockIdx.x * blockDim.x + threadIdx.x;  // 12288*64/8 threads exactly
  int l = g & 63;
  int nt = (g >> 6) & 3;
  int kt = g >> 8;
  int n = nt * 16 + (l & 15);
  int kbase = kt * 32 + ((l >> 4) << 3);
  const float sv = 1.0f / 128.0f;
  s8v o;
#pragma unroll
  for (int j = 0; j < 8; ++j) {
    int k = kbase + j;
    float v = (k < 8192) ? w011[(size_t)k * 64 + n] * sv
                         : w111[(size_t)(k - 8192) * 64 + n] * sv;
    o[j] = f2bf_rne(v);
  }
  *(s8v*)(wf + (size_t)g * 8) = o;
}

// ---------------- shared LDS staging: 64 rows of x ----------------
#define X0_STRIDE 132
#define X1_STRIDE 200

DI void stage_x(const float* __restrict__ x, int b0, float* X0, unsigned short* X1) {
  const int t = threadIdx.x;            // 512 threads
  const int row = t >> 3, l8 = t & 7;
  const float* src = x + (size_t)(b0 + row) * 320;
#pragma unroll
  for (int j = 0; j < 4; ++j) {
    int c = l8 * 16 + j * 4;
    *(f4v*)(&X0[row * X0_STRIDE + c]) = *(const f4v*)(src + c);
  }
  float buf[24];
#pragma unroll
  for (int j = 0; j < 12; ++j) {
    f2v v = *(const f2v*)(src + 128 + l8 * 24 + j * 2);
    buf[2 * j] = v.x; buf[2 * j + 1] = v.y;
  }
#pragma unroll
  for (int i = 0; i < 3; ++i) {
    u4v o;
#pragma unroll
    for (int e = 0; e < 4; ++e)
      o[e] = rpack(buf[(2 * e) * 3 + i], buf[(2 * e + 1) * 3 + i]);
    *(u4v*)(&X1[row * X1_STRIDE + i * 64 + l8 * 8]) = o;
  }
}

// ---------------- A-fragment generators ----------------
DI u4v agen_x0(const float* __restrict__ x0r, float xu, int vb) {
  f4v v0 = *(const f4v*)(x0r + vb);
  f4v v1 = *(const f4v*)(x0r + vb + 4);
  u4v pa;
  pa[0] = rpack(xu * v0.x, xu * v0.y);
  pa[1] = rpack(xu * v0.z, xu * v0.w);
  pa[2] = rpack(xu * v1.x, xu * v1.y);
  pa[3] = rpack(xu * v1.z, xu * v1.w);
  return pa;
}
DI u4v agen_dots(const unsigned short* __restrict__ x1r, int u, int vb) {
  float sm[8] = {0.f, 0.f, 0.f, 0.f, 0.f, 0.f, 0.f, 0.f};
#pragma unroll
  for (int i = 0; i < 3; ++i) {
    const float xu = bf2f(x1r[i * 64 + u]);
    i4v p = *(const i4v*)(x1r + i * 64 + vb);
#pragma unroll
    for (int m = 0; m < 4; ++m) {
      sm[2 * m]     += xu * plo(p[m]);
      sm[2 * m + 1] += xu * phi(p[m]);
    }
  }
  u4v pa;
  pa[0] = rpack(sm[0], sm[1]);
  pa[1] = rpack(sm[2], sm[3]);
  pa[2] = rpack(sm[4], sm[5]);
  pa[3] = rpack(sm[6], sm[7]);
  return pa;
}

// B-frag loaders — ALWAYS called unconditionally (SROA-safe register promotion)
DI void loadB3(s8v* dst, const short* __restrict__ wp, int t) {
#pragma unroll
  for (int nf = 0; nf < 3; ++nf)
    dst[nf] = *(const s8v*)(wp + (size_t)t * 6144 + nf * 512);
}
DI void loadB2(s8v* dst, const short* __restrict__ wp, int t) {
#pragma unroll
  for (int nf = 0; nf < 2; ++nf)
    dst[nf] = *(const s8v*)(wp + (size_t)t * 2048 + nf * 512);
}

// ---------------- scalar-path GEMM: C[8192,192] += A(gen) * Wsc ----------------
// grid 1024 = 128 m-tiles x 8 K-chunks; chunk = blockIdx&7 -> XCD-local (W/XCD = 960 KB, L2-resident)
// block 64 rows x 192 cols; 8 waves = mg(2) x nq(4); wave = 2 m-frags x 3 n-frags (6 MFMA/step)
// regs/wave: 24 AGPR acc + 24 VGPR B ping-pong + ~40 temps -> no spill at 128 cap
__global__ __launch_bounds__(512, 4)
void gemm_sc(const float* __restrict__ x, const short* __restrict__ wf,
             float* __restrict__ acc_out) {
  __shared__ float X0[64 * X0_STRIDE];
  __shared__ unsigned short X1[64 * X1_STRIDE];
  const int c  = blockIdx.x & 7;         // K-chunk, XCD-local
  const int b0 = (blockIdx.x >> 3) * 64;

  stage_x(x, b0, X0, X1);
  __syncthreads();

  const int t0 = threadIdx.x;
  const int w = t0 >> 6, lane = t0 & 63;
  const int mg = w & 1, nq = w >> 1;     // nq in 0..3
  const int q = lane >> 4, r = lane & 15, q8 = (lane >> 4) * 8;
  const int rowA = mg * 32 + r;
  const float* x0A = &X0[rowA * X0_STRIDE];
  const float* x0B = &X0[(rowA + 16) * X0_STRIDE];
  const unsigned short* x1A = &X1[rowA * X1_STRIDE];
  const unsigned short* x1B = &X1[(rowA + 16) * X1_STRIDE];

  f4v acc[2][3];
#pragma unroll
  for (int f = 0; f < 2; ++f)
#pragma unroll
    for (int nf = 0; nf < 3; ++nf) acc[f][nf] = f4v{0.f, 0.f, 0.f, 0.f};

  s8v bA[3], bB[3];

  // ---- region 1: x0 outer product, 64 steps (absolute s in [c*64, +64)) ----
  {
    const int sAbs = c * 64;
    const int u0 = c * 16;               // u advances every 4 steps
    const short* wp = wf + (((size_t)sAbs * 12 + nq * 3) * 64 + lane) * 8;
    loadB3(bA, wp, 0);
    for (int t = 0; t < 64; t += 2) {
      loadB3(bB, wp, t + 1);
      {
        const int u = u0 + (t >> 2), vb = (t & 3) * 32 + q8;
        s8v a0 = __builtin_bit_cast(s8v, agen_x0(x0A, x0A[u], vb));
        s8v a1 = __builtin_bit_cast(s8v, agen_x0(x0B, x0B[u], vb));
#pragma unroll
        for (int nf = 0; nf < 3; ++nf) {
          acc[0][nf] = __builtin_amdgcn_mfma_f32_16x16x32_bf16(a0, bA[nf], acc[0][nf], 0, 0, 0);
          acc[1][nf] = __builtin_amdgcn_mfma_f32_16x16x32_bf16(a1, bA[nf], acc[1][nf], 0, 0, 0);
        }
      }
      loadB3(bA, wp, (t + 2) & 63);      // unconditional; wraps to 0 on last iter
      {
        const int tt = t + 1;
        const int u = u0 + (tt >> 2), vb = (tt & 3) * 32 + q8;
        s8v a0 = __builtin_bit_cast(s8v, agen_x0(x0A, x0A[u], vb));
        s8v a1 = __builtin_bit_cast(s8v, agen_x0(x0B, x0B[u], vb));
#pragma unroll
        for (int nf = 0; nf < 3; ++nf) {
          acc[0][nf] = __builtin_amdgcn_mfma_f32_16x16x32_bf16(a0, bB[nf], acc[0][nf], 0, 0, 0);
          acc[1][nf] = __builtin_amdgcn_mfma_f32_16x16x32_bf16(a1, bB[nf], acc[1][nf], 0, 0, 0);
        }
      }
    }
  }

  // ---- region 2: x1-dots, 16 steps (absolute s in [512 + c*16, +16)) ----
  {
    const int sAbs = 512 + c * 16;
    const int u0 = c * 8;                // u advances every 2 steps
    const short* wp = wf + (((size_t)sAbs * 12 + nq * 3) * 64 + lane) * 8;
    loadB3(bA, wp, 0);
    for (int t = 0; t < 16; t += 2) {
      loadB3(bB, wp, t + 1);
      {
        const int u = u0 + (t >> 1), vb = (t & 1) * 32 + q8;
        s8v a0 = __builtin_bit_cast(s8v, agen_dots(x1A, u, vb));
        s8v a1 = __builtin_bit_cast(s8v, agen_dots(x1B, u, vb));
#pragma unroll
        for (int nf = 0; nf < 3; ++nf) {
          acc[0][nf] = __builtin_amdgcn_mfma_f32_16x16x32_bf16(a0, bA[nf], acc[0][nf], 0, 0, 0);
          acc[1][nf] = __builtin_amdgcn_mfma_f32_16x16x32_bf16(a1, bA[nf], acc[1][nf], 0, 0, 0);
        }
      }
      loadB3(bA, wp, (t + 2) & 15);      // unconditional wrap
      {
        const int tt = t + 1;
        const int u = u0 + (tt >> 1), vb = (tt & 1) * 32 + q8;
        s8v a0 = __builtin_bit_cast(s8v, agen_dots(x1A, u, vb));
        s8v a1 = __builtin_bit_cast(s8v, agen_dots(x1B, u, vb));
#pragma unroll
        for (int nf = 0; nf < 3; ++nf) {
          acc[0][nf] = __builtin_amdgcn_mfma_f32_16x16x32_bf16(a0, bB[nf], acc[0][nf], 0, 0, 0);
          acc[1][nf] = __builtin_amdgcn_mfma_f32_16x16x32_bf16(a1, bB[nf], acc[1][nf], 0, 0, 0);
        }
      }
    }
  }

#pragma unroll
  for (int f = 0; f < 2; ++f)
#pragma unroll
    for (int nf = 0; nf < 3; ++nf) {
      int n = (nq * 3 + nf) * 16 + r;
#pragma unroll
      for (int reg = 0; reg < 4; ++reg) {
        int rowo = b0 + mg * 32 + f * 16 + q * 4 + reg;
        atomicAdd(&acc_out[(size_t)rowo * NW_ + n], acc[f][nf][reg]);
      }
    }
}

// ---------------- vector-path GEMM: C[3*8192, 64] += A(gen) * Wvec ----------------
// grid 1024 = 128 m-tiles x 8 K-chunks (XCD-local); block 64 rows x 3 planes x 64 cols
// 8 waves = mg(4) x nh(2); wave = 1 m-frag x 3 planes x 2 n-frags (6 MFMA/step)
__global__ __launch_bounds__(512, 4)
void gemm_vec(const float* __restrict__ x, const short* __restrict__ wf,
              float* __restrict__ acc_out) {
  __shared__ float X0[64 * X0_STRIDE];
  __shared__ unsigned short X1[64 * X1_STRIDE];
  const int c  = blockIdx.x & 7;
  const int b0 = (blockIdx.x >> 3) * 64;

  stage_x(x, b0, X0, X1);
  __syncthreads();

  const int t0 = threadIdx.x;
  const int w = t0 >> 6, lane = t0 & 63;
  const int mg = w & 3, nh = w >> 2;     // nh in 0..1
  const int q = lane >> 4, r = lane & 15, q8 = (lane >> 4) * 8;
  const int row = mg * 16 + r;
  const float* x0r = &X0[row * X0_STRIDE];
  const unsigned short* x1r = &X1[row * X1_STRIDE];

  f4v acc[3][2];
#pragma unroll
  for (int ip = 0; ip < 3; ++ip)
#pragma unroll
    for (int nf = 0; nf < 2; ++nf) acc[ip][nf] = f4v{0.f, 0.f, 0.f, 0.f};

  s8v bA[2], bB[2];

  // ---- region 1: x0 * x1[ip], 32 steps (absolute s in [c*32, +32)) ----
  {
    const int sAbs = c * 32;
    const int u0 = c * 16;               // u advances every 2 steps
    const short* wp = wf + ((size_t)sAbs * 256 + nh * 2 * 64 + lane) * 8;
    loadB2(bA, wp, 0);
    for (int t = 0; t < 32; t += 2) {
      loadB2(bB, wp, t + 1);
#pragma unroll
      for (int half = 0; half < 2; ++half) {
        const int tt = t + half;
        const int u = u0 + (tt >> 1), vb = (tt & 1) * 32 + q8;
        const float xu = x0r[u];
        const s8v* bfr = (half == 0) ? bA : bB;
#pragma unroll
        for (int i = 0; i < 3; ++i) {
          i4v p = *(const i4v*)(x1r + i * 64 + vb);
          u4v pa;
#pragma unroll
          for (int m = 0; m < 4; ++m)
            pa[m] = rpack(xu * plo(p[m]), xu * phi(p[m]));
          s8v afr = __builtin_bit_cast(s8v, pa);
#pragma unroll
          for (int nf = 0; nf < 2; ++nf)
            acc[i][nf] = __builtin_amdgcn_mfma_f32_16x16x32_bf16(afr, bfr[nf], acc[i][nf], 0, 0, 0);
        }
        if (half == 0) loadB2(bA, wp, (t + 2) & 31);   // unconditional in unrolled half-0
      }
    }
  }

  // ---- region 2: cross products, 16 steps (absolute s in [256 + c*16, +16)) ----
  {
    const int sAbs = 256 + c * 16;
    const int u0 = c * 8;
    const short* wp = wf + ((size_t)sAbs * 256 + nh * 2 * 64 + lane) * 8;
    loadB2(bA, wp, 0);
    for (int t = 0; t < 16; t += 2) {
      loadB2(bB, wp, t + 1);
#pragma unroll
      for (int half = 0; half < 2; ++half) {
        const int tt = t + half;
        const int u = u0 + (tt >> 1), vb = (tt & 1) * 32 + q8;
        const s8v* bfr = (half == 0) ? bA : bB;
        float us[3];
        i4v p[3];
#pragma unroll
        for (int i = 0; i < 3; ++i) {
          us[i] = bf2f(x1r[i * 64 + u]);
          p[i] = *(const i4v*)(x1r + i * 64 + vb);
        }
#pragma unroll
        for (int ip = 0; ip < 3; ++ip) {
          const int i1 = (ip + 1) % 3, i2 = (ip + 2) % 3;
          u4v pa;
#pragma unroll
          for (int m = 0; m < 4; ++m) {
            float lo = us[i1] * plo(p[i2][m]) - us[i2] * plo(p[i1][m]);
            float hi = us[i1] * phi(p[i2][m]) - us[i2] * phi(p[i1][m]);
            pa[m] = rpack(lo, hi);
          }
          s8v afr = __builtin_bit_cast(s8v, pa);
#pragma unroll
          for (int nf = 0; nf < 2; ++nf)
            acc[ip][nf] = __builtin_amdgcn_mfma_f32_16x16x32_bf16(afr, bfr[nf], acc[ip][nf], 0, 0, 0);
        }
        if (half == 0) loadB2(bA, wp, (t + 2) & 15);   // unconditional in unrolled half-0
      }
    }
  }

#pragma unroll
  for (int ip = 0; ip < 3; ++ip)
#pragma unroll
    for (int nf = 0; nf < 2; ++nf) {
      int n = (nh * 2 + nf) * 16 + r;
#pragma unroll
      for (int reg = 0; reg < 4; ++reg) {
        int rowo = ip * B_ + b0 + mg * 16 + q * 4 + reg;
        atomicAdd(&acc_out[(size_t)rowo * 64 + n], acc[ip][nf][reg]);
      }
    }
}

// ---------------- epilogue: silu / sigmoid-gating, interleaved output ----------------
__global__ void epilogue(const float* __restrict__ sc, const float* __restrict__ ve,
                         float* __restrict__ out) {
  int t = blockIdx.x * blockDim.x + threadIdx.x;  // B*192 threads exactly
  int b = t / NW_, c = t % NW_;
  float v = sc[t];
  float sg = 1.0f / (1.0f + __expf(-v));
  if (c < 128) {
    out[(size_t)b * 320 + c] = v * sg;            // silu
  } else {
    int w = c - 128;
#pragma unroll
    for (int i = 0; i < 3; ++i) {
      float vv = ve[((size_t)i * B_ + b) * 64 + w];
      out[(size_t)b * 320 + 128 + w * 3 + i] = vv * sg;
    }
  }
}

// ---------------- launch ----------------
extern "C" void kernel_launch(void* const* d_in, const int* in_sizes, int n_in,
                              void* d_out, int out_size, void* d_ws, size_t ws_size,
                              hipStream_t stream) {
  const float* x    = (const float*)d_in[0];
  const float* w000 = (const float*)d_in[1];
  const float* w110 = (const float*)d_in[2];
  const float* w011 = (const float*)d_in[3];
  const float* w111 = (const float*)d_in[4];
  float* out = (float*)d_out;

  char* ws = (char*)d_ws;
  float* acc_sc = (float*)ws;                     // 8192*192*4  = 6,291,456 B
  float* acc_ve = (float*)(ws + 6291456);         // 3*8192*64*4 = 6,291,456 B
  short* wsc    = (short*)(ws + 12582912);        // 20480*192*2 = 7,864,320 B
  short* wve    = (short*)(ws + 20447232);        // 12288*64*2  = 1,572,864 B

  (void)hipMemsetAsync(acc_sc, 0, 2 * 6291456, stream);  // zero both accumulators
  prep_wsc <<<1920, 256, 0, stream>>>(w000, w110, wsc);
  prep_wvec<<<384,  256, 0, stream>>>(w011, w111, wve);
  gemm_sc  <<<1024, 512, 0, stream>>>(x, wsc, acc_sc);
  gemm_vec <<<1024, 512, 0, stream>>>(x, wve, acc_ve);
  epilogue <<<6144, 256, 0, stream>>>(acc_sc, acc_ve, out);
}